// Round 1
// baseline (519.737 us; speedup 1.0000x reference)
//
#include <hip/hip_runtime.h>
#include <math.h>

#define B_ 4
#define S_ 4096
#define D_ 2048
#define E_ 64
#define NTOK (B_*S_)          // 16384 tokens
#define TPB 32                // tokens per block
#define NCH 8                 // D chunks per block (one per 32-thread group)
#define DCH (D_/NCH)          // 256
#define EPAD 65               // padded expert dim for LDS (bank-conflict-free)

// Block: 256 threads = 8 chunk-groups x 32 tokens. Grid: 512 blocks.
// Each thread accumulates all 64 expert partial dots over its 256-element D-chunk.
// Chunk 0 threads (tid<32) keep partials in registers; chunks 1..7 write LDS.
__global__ __launch_bounds__(256, 2)
void router_kernel(const float* __restrict__ x,
                   const float* __restrict__ W,
                   const float* __restrict__ bias,
                   float* __restrict__ out)
{
    __shared__ float part[NCH - 1][TPB][EPAD];   // 7*32*65*4 = 58240 B
    __shared__ float res[TPB][4];                // p1, p2, (float)i1, (float)i2

    const int tid   = threadIdx.x;
    const int ch    = tid >> 5;        // 0..7
    const int tl    = tid & 31;        // token within block
    const int token = blockIdx.x * TPB + tl;

    const float* __restrict__ xrow  = x + (size_t)token * D_ + ch * DCH;
    const float* __restrict__ wbase = W + ch * DCH;

    float acc[E_];
#pragma unroll
    for (int e = 0; e < E_; ++e) acc[e] = 0.f;

    // Main GEMM loop: d-outer (float4), e-inner fully unrolled.
    // W loads are same-address across all lanes of a wave-half -> L1 broadcast.
    for (int d = 0; d < DCH; d += 4) {
        const float4 xv = *reinterpret_cast<const float4*>(xrow + d);
#pragma unroll
        for (int e = 0; e < E_; ++e) {
            const float4 wv = *reinterpret_cast<const float4*>(wbase + (size_t)e * D_ + d);
            acc[e] = fmaf(xv.x, wv.x,
                     fmaf(xv.y, wv.y,
                     fmaf(xv.z, wv.z,
                     fmaf(xv.w, wv.w, acc[e]))));
        }
    }

    if (ch > 0) {
#pragma unroll
        for (int e = 0; e < E_; ++e) part[ch - 1][tl][e] = acc[e];
    }
    __syncthreads();

    // Reduction + bias + top-2 + 2-way softmax. tid<32 <=> ch==0, tl==tid,
    // so this thread's own acc[] is the chunk-0 partial for token tl.
    if (tid < TPB) {
        const int t = tid;
        float m1 = -INFINITY, m2 = -INFINITY;
        int i1 = 0, i2 = 0;
#pragma unroll 8
        for (int e = 0; e < E_; ++e) {
            float v = acc[e] + bias[e];
#pragma unroll
            for (int c = 0; c < NCH - 1; ++c) v += part[c][t][e];
            // strict > keeps the lowest index on ties, matching lax.top_k
            if (v > m1)      { m2 = m1; i2 = i1; m1 = v; i1 = e; }
            else if (v > m2) { m2 = v;  i2 = e; }
        }
        const float ex = expf(m2 - m1);   // m2 <= m1, stable
        const float den = 1.f + ex;
        res[t][0] = 1.f / den;            // prob at i1
        res[t][1] = ex / den;             // prob at i2
        res[t][2] = (float)i1;
        res[t][3] = (float)i2;
    }
    __syncthreads();

    // Coalesced write of router_output rows (32 tokens x 64 experts = 8192 floats).
    const size_t obase = (size_t)blockIdx.x * TPB * E_;
#pragma unroll
    for (int i = 0; i < (TPB * E_) / 256; ++i) {
        const int f = i * 256 + tid;
        const int t = f >> 6;
        const int e = f & 63;
        const int i1 = (int)res[t][2];
        const int i2 = (int)res[t][3];
        float v = 0.f;
        if (e == i1)      v = res[t][0];
        else if (e == i2) v = res[t][1];
        out[obase + f] = v;
    }

    // ids, stored as float values (whole d_out is interpreted as float32).
    if (tid < TPB * 2) {
        out[(size_t)NTOK * E_ + (size_t)blockIdx.x * (TPB * 2) + tid] =
            res[tid >> 1][2 + (tid & 1)];
    }
}

extern "C" void kernel_launch(void* const* d_in, const int* in_sizes, int n_in,
                              void* d_out, int out_size, void* d_ws, size_t ws_size,
                              hipStream_t stream) {
    const float* x = (const float*)d_in[0];
    const float* W = (const float*)d_in[1];
    const float* b = (const float*)d_in[2];
    float* out     = (float*)d_out;

    dim3 grid(NTOK / TPB);   // 512 blocks
    dim3 block(256);
    hipLaunchKernelGGL(router_kernel, grid, block, 0, stream, x, W, b, out);
}

// Round 2
// 117.227 us; speedup vs baseline: 4.4336x; 4.4336x over previous
//
#include <hip/hip_runtime.h>
#include <math.h>

#define NTOK 16384
#define D_   2048
#define E_   64
#define TPB  64            // tokens per block
#define NW   8             // waves per block = D-splits
#define KQ   (D_/NW)       // 256 k per wave
#define KC   16            // k per staged chunk
#define NCHUNK (KQ/KC)     // 16
#define XS_STRIDE 65       // [KC][65] per-wave x buffer (pad -> conflict-free)
#define XS_WAVE   (KC*XS_STRIDE)   // 1040 floats per wave
#define RB_STRIDE 65
#define RB_SIZE   (TPB*RB_STRIDE)  // 4160 floats per reduce buffer
#define RES_OFF   (NW*XS_WAVE)     // 8320 floats
#define SMEM_FLOATS (RES_OFF + TPB*4)  // 8576 floats = 34.3 KB

// ---- Kernel 1: W (E x D) -> WT (D x E), so W^T[k][0..63] is contiguous ----
__global__ __launch_bounds__(256)
void transpose_w(const float* __restrict__ W, float* __restrict__ wt)
{
    int flat = blockIdx.x * 256 + threadIdx.x;    // 0..32767 output quads
    int k  = flat >> 4;
    int e0 = (flat & 15) * 4;
    float4 v;
    v.x = W[(size_t)(e0+0)*D_ + k];
    v.y = W[(size_t)(e0+1)*D_ + k];
    v.z = W[(size_t)(e0+2)*D_ + k];
    v.w = W[(size_t)(e0+3)*D_ + k];
    *reinterpret_cast<float4*>(wt + (size_t)k*E_ + e0) = v;
}

// ---- Kernel 2: main router ----
// Block: 512 threads = 8 waves. Wave q handles k in [q*KQ, q*KQ+KQ) for the
// block's 64 tokens (lane = token). W^T rows come in via scalar loads (SGPR
// operand to v_fma). x staged coalesced global->LDS, [k][token] layout.
__global__ __launch_bounds__(512)
void router_main(const float* __restrict__ x,
                 const float* __restrict__ wt,
                 const float* __restrict__ bias,
                 float* __restrict__ out)
{
    __shared__ float smem[SMEM_FLOATS];

    const int tid  = threadIdx.x;
    const int lane = tid & 63;
    const int q    = __builtin_amdgcn_readfirstlane(tid >> 6);
    const int T0   = blockIdx.x * TPB;

    float* xs = smem + q * XS_WAVE;

    float acc[E_];
#pragma unroll
    for (int e = 0; e < E_; ++e) acc[e] = 0.f;

    // staging map: lane -> (tsub = lane>>2, ksub = (lane&3)*4), 4 passes of 16 tokens
    const int tsub = lane >> 2;
    const int ksub = (lane & 3) * 4;
    const float* xbase = x + (size_t)(T0 + tsub) * D_ + q * KQ + ksub;

    float4 pre[4];
#pragma unroll
    for (int p = 0; p < 4; ++p)
        pre[p] = *reinterpret_cast<const float4*>(xbase + (size_t)p * 16 * D_);

    for (int c = 0; c < NCHUNK; ++c) {
        // write staged chunk into LDS (transposed: xs[k][token])
#pragma unroll
        for (int p = 0; p < 4; ++p) {
            const int t = tsub + p * 16;
            xs[(ksub+0)*XS_STRIDE + t] = pre[p].x;
            xs[(ksub+1)*XS_STRIDE + t] = pre[p].y;
            xs[(ksub+2)*XS_STRIDE + t] = pre[p].z;
            xs[(ksub+3)*XS_STRIDE + t] = pre[p].w;
        }
        // prefetch next chunk (latency hides under the FMA block below)
        if (c + 1 < NCHUNK) {
#pragma unroll
            for (int p = 0; p < 4; ++p)
                pre[p] = *reinterpret_cast<const float4*>(xbase + (size_t)p * 16 * D_ + (c+1) * KC);
        }
        const float* wk = wt + (size_t)(q * KQ + c * KC) * E_;
#pragma unroll 4
        for (int kk = 0; kk < KC; ++kk) {
            const float xv = xs[kk * XS_STRIDE + lane];
#pragma unroll
            for (int e = 0; e < E_; ++e)
                acc[e] = fmaf(xv, wk[kk * E_ + e], acc[e]);
        }
    }

    // ---- tree-reduce the 8 k-partials (2 LDS buffers, deterministic) ----
    float* rb = smem;                 // 2 buffers of RB_SIZE (overlaps xs area)
    __syncthreads();
    // round 0a: waves 4,5 -> 0,1
    if (q == 4 || q == 5) {
        float* b = rb + (q - 4) * RB_SIZE;
#pragma unroll
        for (int e = 0; e < E_; ++e) b[lane * RB_STRIDE + e] = acc[e];
    }
    __syncthreads();
    if (q == 0 || q == 1) {
        const float* b = rb + q * RB_SIZE;
#pragma unroll
        for (int e = 0; e < E_; ++e) acc[e] += b[lane * RB_STRIDE + e];
    }
    __syncthreads();
    // round 0b: waves 6,7 -> 2,3
    if (q == 6 || q == 7) {
        float* b = rb + (q - 6) * RB_SIZE;
#pragma unroll
        for (int e = 0; e < E_; ++e) b[lane * RB_STRIDE + e] = acc[e];
    }
    __syncthreads();
    if (q == 2 || q == 3) {
        const float* b = rb + (q - 2) * RB_SIZE;
#pragma unroll
        for (int e = 0; e < E_; ++e) acc[e] += b[lane * RB_STRIDE + e];
    }
    __syncthreads();
    // round 1: waves 2,3 -> 0,1
    if (q == 2 || q == 3) {
        float* b = rb + (q - 2) * RB_SIZE;
#pragma unroll
        for (int e = 0; e < E_; ++e) b[lane * RB_STRIDE + e] = acc[e];
    }
    __syncthreads();
    if (q == 0 || q == 1) {
        const float* b = rb + q * RB_SIZE;
#pragma unroll
        for (int e = 0; e < E_; ++e) acc[e] += b[lane * RB_STRIDE + e];
    }
    __syncthreads();
    // round 2: wave 1 -> 0
    if (q == 1) {
#pragma unroll
        for (int e = 0; e < E_; ++e) rb[lane * RB_STRIDE + e] = acc[e];
    }
    __syncthreads();

    float* res = smem + RES_OFF;      // [64][4]: p1, p2, i1, i2
    if (q == 0) {
#pragma unroll
        for (int e = 0; e < E_; ++e) acc[e] += rb[lane * RB_STRIDE + e];
        float m1 = -INFINITY, m2 = -INFINITY;
        int i1 = 0, i2 = 0;
#pragma unroll 8
        for (int e = 0; e < E_; ++e) {
            const float v = acc[e] + bias[e];
            if (v > m1)      { m2 = m1; i2 = i1; m1 = v; i1 = e; }
            else if (v > m2) { m2 = v;  i2 = e; }
        }
        const float ex  = expf(m2 - m1);
        const float den = 1.f + ex;
        res[lane*4+0] = 1.f / den;
        res[lane*4+1] = ex / den;
        res[lane*4+2] = (float)i1;
        res[lane*4+3] = (float)i2;
    }
    __syncthreads();

    // ---- coalesced output: probs (64 tokens x 64 experts) ----
    const size_t obase = (size_t)T0 * E_;
#pragma unroll
    for (int i = 0; i < (TPB * E_) / 512; ++i) {   // 8 iters
        const int f = i * 512 + tid;
        const int t = f >> 6;
        const int e = f & 63;
        const float p1 = res[t*4+0];
        const float p2 = res[t*4+1];
        const int   i1 = (int)res[t*4+2];
        const int   i2 = (int)res[t*4+3];
        float v = 0.f;
        if (e == i1)      v = p1;
        else if (e == i2) v = p2;
        out[obase + f] = v;
    }
    // ids as float values (whole d_out is read as float32)
    if (tid < TPB * 2) {
        out[(size_t)NTOK * E_ + (size_t)T0 * 2 + tid] =
            res[(tid >> 1) * 4 + 2 + (tid & 1)];
    }
}

extern "C" void kernel_launch(void* const* d_in, const int* in_sizes, int n_in,
                              void* d_out, int out_size, void* d_ws, size_t ws_size,
                              hipStream_t stream) {
    const float* x = (const float*)d_in[0];
    const float* W = (const float*)d_in[1];
    const float* b = (const float*)d_in[2];
    float* out     = (float*)d_out;
    float* wt      = (float*)d_ws;    // 2048*64*4 = 512 KB

    hipLaunchKernelGGL(transpose_w, dim3(128), dim3(256), 0, stream, W, wt);
    hipLaunchKernelGGL(router_main, dim3(NTOK / TPB), dim3(512), 0, stream,
                       x, wt, b, out);
}

// Round 3
// 117.033 us; speedup vs baseline: 4.4409x; 1.0017x over previous
//
#include <hip/hip_runtime.h>
#include <math.h>

#define NTOK 16384
#define D_   2048
#define E_   64
#define TPB  64            // tokens per block
#define NW   8             // waves per block = D-splits
#define KQ   (D_/NW)       // 256 k per wave
#define KC   16            // k per staged chunk
#define NCHUNK (KQ/KC)     // 16
#define XS_STRIDE 65       // [KC][65] per-wave x buffer (pad -> conflict-free)
#define XS_WAVE   (KC*XS_STRIDE)   // 1040 floats per wave
#define RB_STRIDE 65
#define RB_SIZE   (TPB*RB_STRIDE)  // 4160 floats per reduce buffer
#define RES_OFF   (NW*XS_WAVE)     // 8320 floats
#define SMEM_FLOATS (RES_OFF + TPB*4)  // 8576 floats = 34.3 KB

// ---- Kernel 1: W (E x D) -> WT (D x E), so W^T[k][0..63] is contiguous ----
__global__ __launch_bounds__(256)
void transpose_w(const float* __restrict__ W, float* __restrict__ wt)
{
    int flat = blockIdx.x * 256 + threadIdx.x;    // 0..32767 output quads
    int k  = flat >> 4;
    int e0 = (flat & 15) * 4;
    float4 v;
    v.x = W[(size_t)(e0+0)*D_ + k];
    v.y = W[(size_t)(e0+1)*D_ + k];
    v.z = W[(size_t)(e0+2)*D_ + k];
    v.w = W[(size_t)(e0+3)*D_ + k];
    *reinterpret_cast<float4*>(wt + (size_t)k*E_ + e0) = v;
}

// ---- Kernel 2: main router ----
// Block: 512 threads = 8 waves. Wave q handles k in [q*KQ, q*KQ+KQ) for the
// block's 64 tokens (lane = token). W^T rows come in via scalar loads (SGPR
// operand to v_fma). x staged coalesced global->LDS, [k][token] layout.
// __launch_bounds__(512, 2): 2 waves/SIMD min -> 256-VGPR budget, so acc[64]
// stays in registers (round-2's (512) default capped VGPRs at 48 -> spill,
// 90 MB scratch writes).
__global__ __launch_bounds__(512, 2)
void router_main(const float* __restrict__ x,
                 const float* __restrict__ wt,
                 const float* __restrict__ bias,
                 float* __restrict__ out)
{
    __shared__ float smem[SMEM_FLOATS];

    const int tid  = threadIdx.x;
    const int lane = tid & 63;
    const int q    = __builtin_amdgcn_readfirstlane(tid >> 6);
    const int T0   = blockIdx.x * TPB;

    float* xs = smem + q * XS_WAVE;

    float acc[E_];
#pragma unroll
    for (int e = 0; e < E_; ++e) acc[e] = 0.f;

    // staging map: lane -> (tsub = lane>>2, ksub = (lane&3)*4), 4 passes of 16 tokens
    const int tsub = lane >> 2;
    const int ksub = (lane & 3) * 4;
    const float* xbase = x + (size_t)(T0 + tsub) * D_ + q * KQ + ksub;

    float4 pre[4];
#pragma unroll
    for (int p = 0; p < 4; ++p)
        pre[p] = *reinterpret_cast<const float4*>(xbase + (size_t)p * 16 * D_);

    for (int c = 0; c < NCHUNK; ++c) {
        // write staged chunk into LDS (transposed: xs[k][token])
#pragma unroll
        for (int p = 0; p < 4; ++p) {
            const int t = tsub + p * 16;
            xs[(ksub+0)*XS_STRIDE + t] = pre[p].x;
            xs[(ksub+1)*XS_STRIDE + t] = pre[p].y;
            xs[(ksub+2)*XS_STRIDE + t] = pre[p].z;
            xs[(ksub+3)*XS_STRIDE + t] = pre[p].w;
        }
        // prefetch next chunk (latency hides under the FMA block below)
        if (c + 1 < NCHUNK) {
#pragma unroll
            for (int p = 0; p < 4; ++p)
                pre[p] = *reinterpret_cast<const float4*>(xbase + (size_t)p * 16 * D_ + (c+1) * KC);
        }
        const float* wk = wt + (size_t)(q * KQ + c * KC) * E_;
#pragma unroll 4
        for (int kk = 0; kk < KC; ++kk) {
            const float xv = xs[kk * XS_STRIDE + lane];
#pragma unroll
            for (int e = 0; e < E_; ++e)
                acc[e] = fmaf(xv, wk[kk * E_ + e], acc[e]);
        }
    }

    // ---- tree-reduce the 8 k-partials (2 LDS buffers, deterministic) ----
    float* rb = smem;                 // 2 buffers of RB_SIZE (overlaps xs area)
    __syncthreads();
    // round 0a: waves 4,5 -> 0,1
    if (q == 4 || q == 5) {
        float* b = rb + (q - 4) * RB_SIZE;
#pragma unroll
        for (int e = 0; e < E_; ++e) b[lane * RB_STRIDE + e] = acc[e];
    }
    __syncthreads();
    if (q == 0 || q == 1) {
        const float* b = rb + q * RB_SIZE;
#pragma unroll
        for (int e = 0; e < E_; ++e) acc[e] += b[lane * RB_STRIDE + e];
    }
    __syncthreads();
    // round 0b: waves 6,7 -> 2,3
    if (q == 6 || q == 7) {
        float* b = rb + (q - 6) * RB_SIZE;
#pragma unroll
        for (int e = 0; e < E_; ++e) b[lane * RB_STRIDE + e] = acc[e];
    }
    __syncthreads();
    if (q == 2 || q == 3) {
        const float* b = rb + (q - 2) * RB_SIZE;
#pragma unroll
        for (int e = 0; e < E_; ++e) acc[e] += b[lane * RB_STRIDE + e];
    }
    __syncthreads();
    // round 1: waves 2,3 -> 0,1
    if (q == 2 || q == 3) {
        float* b = rb + (q - 2) * RB_SIZE;
#pragma unroll
        for (int e = 0; e < E_; ++e) b[lane * RB_STRIDE + e] = acc[e];
    }
    __syncthreads();
    if (q == 0 || q == 1) {
        const float* b = rb + q * RB_SIZE;
#pragma unroll
        for (int e = 0; e < E_; ++e) acc[e] += b[lane * RB_STRIDE + e];
    }
    __syncthreads();
    // round 2: wave 1 -> 0
    if (q == 1) {
#pragma unroll
        for (int e = 0; e < E_; ++e) rb[lane * RB_STRIDE + e] = acc[e];
    }
    __syncthreads();

    float* res = smem + RES_OFF;      // [64][4]: p1, p2, i1, i2
    if (q == 0) {
#pragma unroll
        for (int e = 0; e < E_; ++e) acc[e] += rb[lane * RB_STRIDE + e];
        float m1 = -INFINITY, m2 = -INFINITY;
        int i1 = 0, i2 = 0;
#pragma unroll 8
        for (int e = 0; e < E_; ++e) {
            const float v = acc[e] + bias[e];
            if (v > m1)      { m2 = m1; i2 = i1; m1 = v; i1 = e; }
            else if (v > m2) { m2 = v;  i2 = e; }
        }
        const float ex  = expf(m2 - m1);
        const float den = 1.f + ex;
        res[lane*4+0] = 1.f / den;
        res[lane*4+1] = ex / den;
        res[lane*4+2] = (float)i1;
        res[lane*4+3] = (float)i2;
    }
    __syncthreads();

    // ---- coalesced output: probs (64 tokens x 64 experts) ----
    const size_t obase = (size_t)T0 * E_;
#pragma unroll
    for (int i = 0; i < (TPB * E_) / 512; ++i) {   // 8 iters
        const int f = i * 512 + tid;
        const int t = f >> 6;
        const int e = f & 63;
        const float p1 = res[t*4+0];
        const float p2 = res[t*4+1];
        const int   i1 = (int)res[t*4+2];
        const int   i2 = (int)res[t*4+3];
        float v = 0.f;
        if (e == i1)      v = p1;
        else if (e == i2) v = p2;
        out[obase + f] = v;
    }
    // ids as float values (whole d_out is read as float32)
    if (tid < TPB * 2) {
        out[(size_t)NTOK * E_ + (size_t)T0 * 2 + tid] =
            res[(tid >> 1) * 4 + 2 + (tid & 1)];
    }
}

extern "C" void kernel_launch(void* const* d_in, const int* in_sizes, int n_in,
                              void* d_out, int out_size, void* d_ws, size_t ws_size,
                              hipStream_t stream) {
    const float* x = (const float*)d_in[0];
    const float* W = (const float*)d_in[1];
    const float* b = (const float*)d_in[2];
    float* out     = (float*)d_out;
    float* wt      = (float*)d_ws;    // 2048*64*4 = 512 KB

    hipLaunchKernelGGL(transpose_w, dim3(128), dim3(256), 0, stream, W, wt);
    hipLaunchKernelGGL(router_main, dim3(NTOK / TPB), dim3(512), 0, stream,
                       x, wt, b, out);
}

// Round 4
// 104.775 us; speedup vs baseline: 4.9605x; 1.1170x over previous
//
#include <hip/hip_runtime.h>
#include <math.h>

#define NTOK 16384
#define D_   2048
#define E_   64
#define TPB  64            // tokens per block
#define NW   8             // waves per block = D-splits
#define KQ   (D_/NW)       // 256 k per wave
#define KC   16            // k per staged chunk
#define NCHUNK (KQ/KC)     // 16
#define XS_STRIDE 65       // [KC][65] per-wave x buffer (pad -> conflict-free)
#define XS_WAVE   (KC*XS_STRIDE)   // 1040 floats per wave
#define RB_STRIDE 65
#define RB_SIZE   (TPB*RB_STRIDE)  // 4160 floats per reduce buffer
#define RES_OFF   (NW*XS_WAVE)     // 8320 floats
#define SMEM_FLOATS (RES_OFF + TPB*4)  // 8576 floats = 34.3 KB

// ---- Kernel 1: W (E x D) -> WT (D x E), so W^T[k][0..63] is contiguous ----
__global__ __launch_bounds__(256)
void transpose_w(const float* __restrict__ W, float* __restrict__ wt)
{
    int flat = blockIdx.x * 256 + threadIdx.x;    // 0..32767 output quads
    int k  = flat >> 4;
    int e0 = (flat & 15) * 4;
    float4 v;
    v.x = W[(size_t)(e0+0)*D_ + k];
    v.y = W[(size_t)(e0+1)*D_ + k];
    v.z = W[(size_t)(e0+2)*D_ + k];
    v.w = W[(size_t)(e0+3)*D_ + k];
    *reinterpret_cast<float4*>(wt + (size_t)k*E_ + e0) = v;
}

// ---- Kernel 2: main router ----
// Block: 512 threads = 8 waves. Wave q handles k in [q*KQ, q*KQ+KQ) for the
// block's 64 tokens (lane = token). W^T rows come in via uniform-address
// loads. x staged coalesced global->LDS, [k][token] layout.
//
// CRITICAL (rule #20): every access to acc[] must be a compile-time index.
// Round 2/3 used "#pragma unroll 8" (partial) on the top-2 scan -> runtime
// acc[e] -> the whole acc[64] demoted to scratch (VGPR=48, 85 MB of scratch
// HBM traffic, 117 us). All acc loops below are FULLY unrolled.
__global__ __launch_bounds__(512, 2)
void router_main(const float* __restrict__ x,
                 const float* __restrict__ wt,
                 const float* __restrict__ bias,
                 float* __restrict__ out)
{
    __shared__ float smem[SMEM_FLOATS];

    const int tid  = threadIdx.x;
    const int lane = tid & 63;
    const int q    = __builtin_amdgcn_readfirstlane(tid >> 6);
    const int T0   = blockIdx.x * TPB;

    float* xs = smem + q * XS_WAVE;

    float acc[E_];
#pragma unroll
    for (int e = 0; e < E_; ++e) acc[e] = 0.f;

    // staging map: lane -> (tsub = lane>>2, ksub = (lane&3)*4), 4 passes of 16 tokens
    const int tsub = lane >> 2;
    const int ksub = (lane & 3) * 4;
    const float* xbase = x + (size_t)(T0 + tsub) * D_ + q * KQ + ksub;

    float4 pre[4];
#pragma unroll
    for (int p = 0; p < 4; ++p)
        pre[p] = *reinterpret_cast<const float4*>(xbase + (size_t)p * 16 * D_);

    for (int c = 0; c < NCHUNK; ++c) {
        // write staged chunk into LDS (transposed: xs[k][token])
#pragma unroll
        for (int p = 0; p < 4; ++p) {
            const int t = tsub + p * 16;
            xs[(ksub+0)*XS_STRIDE + t] = pre[p].x;
            xs[(ksub+1)*XS_STRIDE + t] = pre[p].y;
            xs[(ksub+2)*XS_STRIDE + t] = pre[p].z;
            xs[(ksub+3)*XS_STRIDE + t] = pre[p].w;
        }
        // prefetch next chunk (latency hides under the FMA block below)
        if (c + 1 < NCHUNK) {
#pragma unroll
            for (int p = 0; p < 4; ++p)
                pre[p] = *reinterpret_cast<const float4*>(xbase + (size_t)p * 16 * D_ + (c+1) * KC);
        }
        const float* wk = wt + (size_t)(q * KQ + c * KC) * E_;
#pragma unroll 4
        for (int kk = 0; kk < KC; ++kk) {
            const float xv = xs[kk * XS_STRIDE + lane];
#pragma unroll
            for (int e = 0; e < E_; ++e)
                acc[e] = fmaf(xv, wk[kk * E_ + e], acc[e]);
        }
    }

    // ---- tree-reduce the 8 k-partials (2 LDS buffers, deterministic) ----
    float* rb = smem;                 // 2 buffers of RB_SIZE (overlaps xs area)
    __syncthreads();
    // round 0a: waves 4,5 -> 0,1
    if (q == 4 || q == 5) {
        float* b = rb + (q - 4) * RB_SIZE;
#pragma unroll
        for (int e = 0; e < E_; ++e) b[lane * RB_STRIDE + e] = acc[e];
    }
    __syncthreads();
    if (q == 0 || q == 1) {
        const float* b = rb + q * RB_SIZE;
#pragma unroll
        for (int e = 0; e < E_; ++e) acc[e] += b[lane * RB_STRIDE + e];
    }
    __syncthreads();
    // round 0b: waves 6,7 -> 2,3
    if (q == 6 || q == 7) {
        float* b = rb + (q - 6) * RB_SIZE;
#pragma unroll
        for (int e = 0; e < E_; ++e) b[lane * RB_STRIDE + e] = acc[e];
    }
    __syncthreads();
    if (q == 2 || q == 3) {
        const float* b = rb + (q - 2) * RB_SIZE;
#pragma unroll
        for (int e = 0; e < E_; ++e) acc[e] += b[lane * RB_STRIDE + e];
    }
    __syncthreads();
    // round 1: waves 2,3 -> 0,1
    if (q == 2 || q == 3) {
        float* b = rb + (q - 2) * RB_SIZE;
#pragma unroll
        for (int e = 0; e < E_; ++e) b[lane * RB_STRIDE + e] = acc[e];
    }
    __syncthreads();
    if (q == 0 || q == 1) {
        const float* b = rb + q * RB_SIZE;
#pragma unroll
        for (int e = 0; e < E_; ++e) acc[e] += b[lane * RB_STRIDE + e];
    }
    __syncthreads();
    // round 2: wave 1 -> 0
    if (q == 1) {
#pragma unroll
        for (int e = 0; e < E_; ++e) rb[lane * RB_STRIDE + e] = acc[e];
    }
    __syncthreads();

    float* res = smem + RES_OFF;      // [64][4]: p1, p2, i1, i2
    if (q == 0) {
#pragma unroll
        for (int e = 0; e < E_; ++e) acc[e] += rb[lane * RB_STRIDE + e];
        float m1 = -INFINITY, m2 = -INFINITY;
        int i1 = 0, i2 = 0;
        // FULL unroll: acc[e] must be compile-time indexed (rule #20)
#pragma unroll
        for (int e = 0; e < E_; ++e) {
            const float v = acc[e] + bias[e];
            if (v > m1)      { m2 = m1; i2 = i1; m1 = v; i1 = e; }
            else if (v > m2) { m2 = v;  i2 = e; }
        }
        const float ex  = expf(m2 - m1);
        const float den = 1.f + ex;
        res[lane*4+0] = 1.f / den;
        res[lane*4+1] = ex / den;
        res[lane*4+2] = (float)i1;
        res[lane*4+3] = (float)i2;
    }
    __syncthreads();

    // ---- coalesced output: probs (64 tokens x 64 experts) ----
    const size_t obase = (size_t)T0 * E_;
#pragma unroll
    for (int i = 0; i < (TPB * E_) / 512; ++i) {   // 8 iters
        const int f = i * 512 + tid;
        const int t = f >> 6;
        const int e = f & 63;
        const float p1 = res[t*4+0];
        const float p2 = res[t*4+1];
        const int   i1 = (int)res[t*4+2];
        const int   i2 = (int)res[t*4+3];
        float v = 0.f;
        if (e == i1)      v = p1;
        else if (e == i2) v = p2;
        out[obase + f] = v;
    }
    // ids as float values (whole d_out is read as float32)
    if (tid < TPB * 2) {
        out[(size_t)NTOK * E_ + (size_t)T0 * 2 + tid] =
            res[(tid >> 1) * 4 + 2 + (tid & 1)];
    }
}

extern "C" void kernel_launch(void* const* d_in, const int* in_sizes, int n_in,
                              void* d_out, int out_size, void* d_ws, size_t ws_size,
                              hipStream_t stream) {
    const float* x = (const float*)d_in[0];
    const float* W = (const float*)d_in[1];
    const float* b = (const float*)d_in[2];
    float* out     = (float*)d_out;
    float* wt      = (float*)d_ws;    // 2048*64*4 = 512 KB

    hipLaunchKernelGGL(transpose_w, dim3(128), dim3(256), 0, stream, W, wt);
    hipLaunchKernelGGL(router_main, dim3(NTOK / TPB), dim3(512), 0, stream,
                       x, wt, b, out);
}

// Round 5
// 76.211 us; speedup vs baseline: 6.8197x; 1.3748x over previous
//
#include <hip/hip_runtime.h>
#include <math.h>

#define NTOK 16384
#define D_   2048
#define E_   64
#define TPB  64            // tokens per block
#define NKC  (D_/32)       // 64 k32-steps

typedef _Float16 f16x8 __attribute__((ext_vector_type(8)));
typedef float    f32x4 __attribute__((ext_vector_type(4)));

#define LSCALE      256.0f          // pre-scale x and W before f16 split (denorm guard)
#define LSCALE2_INV (1.0f/65536.0f) // exact pow2 un-scale of acc

#define LOG_STRIDE 65
#define RES_OFF    (TPB*LOG_STRIDE)       // 4160
#define SMEM_FLOATS (RES_OFF + TPB*4)     // 4416 floats = 17.7 KB

// ---- Kernel 1: W (E x D fp32) -> fragment-ordered f16 hi/lo, scaled x256 ----
// Fragment order: element j of lane l for (n-tile nt, k32-step kc) is
//   W[e = nt*16 + (l&15)][k = kc*32 + (l>>4)*4 + (j&3) + (j>=4 ? 16 : 0)]
// The SAME k-map is used for the A operand, so any deviation from the true
// HW k-order cancels in the contraction.
__global__ __launch_bounds__(256)
void prep_w(const float* __restrict__ W,
            _Float16* __restrict__ wh, _Float16* __restrict__ wl)
{
    const int idx = blockIdx.x * 256 + threadIdx.x;   // 0..16383
    const int l  = idx & 63;
    const int kc = (idx >> 6) & 63;
    const int nt = idx >> 12;                          // 0..3
    const int e  = nt * 16 + (l & 15);
    const int g  = l >> 4;
    const float* src = W + (size_t)e * D_ + kc * 32 + g * 4;
    const float4 f0 = *reinterpret_cast<const float4*>(src);
    const float4 f1 = *reinterpret_cast<const float4*>(src + 16);
    const float v[8] = {f0.x, f0.y, f0.z, f0.w, f1.x, f1.y, f1.z, f1.w};
    f16x8 h, lo;
#pragma unroll
    for (int j = 0; j < 8; ++j) {
        const float vs = v[j] * LSCALE;
        const _Float16 hj = (_Float16)vs;
        h[j]  = hj;
        lo[j] = (_Float16)(vs - (float)hj);
    }
    *reinterpret_cast<f16x8*>(wh + (size_t)idx * 8) = h;
    *reinterpret_cast<f16x8*>(wl + (size_t)idx * 8) = lo;
}

// ---- Kernel 2: MFMA router ----
// 256 blocks x 512 threads (8 waves). Block owns 64 tokens.
// Wave w: m-tile mt = w>>1 (16 tokens), n-pair np = w&1 (experts np*32..+31).
// Full K per wave -> no cross-wave reduction. 3 MFMAs per (tile, k32):
// hh + lh + hl (ll term ~2^-22 relative, dropped).
__global__ __launch_bounds__(512, 2)
void router_mfma(const float* __restrict__ x,
                 const _Float16* __restrict__ wh,
                 const _Float16* __restrict__ wl,
                 const float* __restrict__ bias,
                 float* __restrict__ out)
{
    __shared__ float smem[SMEM_FLOATS];   // logits [64][65] + res [64][4]

    const int tid = threadIdx.x;
    const int l   = tid & 63;
    const int w   = __builtin_amdgcn_readfirstlane(tid >> 6);
    const int mt  = w >> 1;
    const int np  = w & 1;
    const int T0  = blockIdx.x * TPB;
    const int g   = l >> 4;

    const float* xp = x + (size_t)(T0 + mt * 16 + (l & 15)) * D_ + g * 4;
    // B fragments: offset = ((nt*64 + kc)*64 + l)*8 halves
    const size_t boff0 = ((size_t)(2 * np)     * NKC * 64 + l) * 8;
    const size_t boff1 = ((size_t)(2 * np + 1) * NKC * 64 + l) * 8;

    f32x4 acc0 = {0.f, 0.f, 0.f, 0.f};
    f32x4 acc1 = {0.f, 0.f, 0.f, 0.f};

    for (int kc = 0; kc < NKC; ++kc) {
        // A fragment: 8 floats of x (k-map matches prep_w)
        const float4 xa = *reinterpret_cast<const float4*>(xp + kc * 32);
        const float4 xb = *reinterpret_cast<const float4*>(xp + kc * 32 + 16);
        const float av[8] = {xa.x, xa.y, xa.z, xa.w, xb.x, xb.y, xb.z, xb.w};
        f16x8 ah, al;
#pragma unroll
        for (int j = 0; j < 8; ++j) {
            const float vs = av[j] * LSCALE;
            const _Float16 hj = (_Float16)vs;
            ah[j] = hj;
            al[j] = (_Float16)(vs - (float)hj);
        }
        const size_t kco = (size_t)kc * 512;
        const f16x8 b0h = *reinterpret_cast<const f16x8*>(wh + boff0 + kco);
        const f16x8 b0l = *reinterpret_cast<const f16x8*>(wl + boff0 + kco);
        const f16x8 b1h = *reinterpret_cast<const f16x8*>(wh + boff1 + kco);
        const f16x8 b1l = *reinterpret_cast<const f16x8*>(wl + boff1 + kco);

        acc0 = __builtin_amdgcn_mfma_f32_16x16x32_f16(ah, b0h, acc0, 0, 0, 0);
        acc0 = __builtin_amdgcn_mfma_f32_16x16x32_f16(al, b0h, acc0, 0, 0, 0);
        acc0 = __builtin_amdgcn_mfma_f32_16x16x32_f16(ah, b0l, acc0, 0, 0, 0);
        acc1 = __builtin_amdgcn_mfma_f32_16x16x32_f16(ah, b1h, acc1, 0, 0, 0);
        acc1 = __builtin_amdgcn_mfma_f32_16x16x32_f16(al, b1h, acc1, 0, 0, 0);
        acc1 = __builtin_amdgcn_mfma_f32_16x16x32_f16(ah, b1l, acc1, 0, 0, 0);

        __syncthreads();   // lockstep -> L1 dedups shared B/x lines across waves
    }

    // ---- C tiles -> LDS logits. C layout: col = lane&15, row = (lane>>4)*4 + r ----
    {
        const int row0 = mt * 16 + g * 4;
        const int col0 = (2 * np) * 16 + (l & 15);
#pragma unroll
        for (int r = 0; r < 4; ++r) {
            smem[(row0 + r) * LOG_STRIDE + col0]      = acc0[r] * LSCALE2_INV;
            smem[(row0 + r) * LOG_STRIDE + col0 + 16] = acc1[r] * LSCALE2_INV;
        }
    }
    __syncthreads();

    // ---- top-2 + 2-way softmax: thread t scans token t's 64 logits ----
    float* res = smem + RES_OFF;
    if (tid < TPB) {
        const int t = tid;
        float m1 = -INFINITY, m2 = -INFINITY;
        int i1 = 0, i2 = 0;
        for (int e = 0; e < E_; ++e) {
            const float v = smem[t * LOG_STRIDE + e] + bias[e];
            if (v > m1)      { m2 = m1; i2 = i1; m1 = v; i1 = e; }
            else if (v > m2) { m2 = v;  i2 = e; }
        }
        const float ex  = expf(m2 - m1);
        const float den = 1.f + ex;
        res[t*4+0] = 1.f / den;
        res[t*4+1] = ex / den;
        res[t*4+2] = (float)i1;
        res[t*4+3] = (float)i2;
    }
    __syncthreads();

    // ---- coalesced output: probs (64 tokens x 64 experts) ----
    const size_t obase = (size_t)T0 * E_;
#pragma unroll
    for (int i = 0; i < (TPB * E_) / 512; ++i) {   // 8 iters
        const int f = i * 512 + tid;
        const int t = f >> 6;
        const int e = f & 63;
        const float p1 = res[t*4+0];
        const float p2 = res[t*4+1];
        const int   i1 = (int)res[t*4+2];
        const int   i2 = (int)res[t*4+3];
        float v = 0.f;
        if (e == i1)      v = p1;
        else if (e == i2) v = p2;
        out[obase + f] = v;
    }
    // ids as float values (whole d_out is read as float32)
    if (tid < TPB * 2) {
        out[(size_t)NTOK * E_ + (size_t)T0 * 2 + tid] =
            res[(tid >> 1) * 4 + 2 + (tid & 1)];
    }
}

extern "C" void kernel_launch(void* const* d_in, const int* in_sizes, int n_in,
                              void* d_out, int out_size, void* d_ws, size_t ws_size,
                              hipStream_t stream) {
    const float* x = (const float*)d_in[0];
    const float* W = (const float*)d_in[1];
    const float* b = (const float*)d_in[2];
    float* out     = (float*)d_out;
    _Float16* wh   = (_Float16*)d_ws;                       // 256 KB
    _Float16* wl   = wh + (size_t)4 * NKC * 64 * 8;         // +256 KB

    hipLaunchKernelGGL(prep_w, dim3(64), dim3(256), 0, stream, W, wh, wl);
    hipLaunchKernelGGL(router_mfma, dim3(NTOK / TPB), dim3(512), 0, stream,
                       x, wh, wl, b, out);
}